// Round 1
// baseline (102.296 us; speedup 1.0000x reference)
//
#include <hip/hip_runtime.h>
#include <hip/hip_bf16.h>

typedef unsigned short u16;
typedef __attribute__((ext_vector_type(8))) short short8;
typedef __attribute__((ext_vector_type(4))) float f32x4;

#define HEADS 8
#define HID 64

__device__ inline u16 f2bf(float f){
    unsigned u = __float_as_uint(f);
    unsigned r = (u + 0x7fffu + ((u >> 16) & 1u)) >> 16;
    return (u16)r;
}

// ---------------- kernel 0: weight prep (transpose -> bf16) ----------------
// WqT/WkT/WvT: [512][256]  WT[c][d] = W[c/64][d][c%64]
// WoT: [256][512]          WoT[o][k] = Wo[k][o]
__global__ __launch_bounds__(256) void prep_weights(
    const float* __restrict__ Wq, const float* __restrict__ Wk,
    const float* __restrict__ Wv, const float* __restrict__ Wo,
    u16* __restrict__ WqT, u16* __restrict__ WkT, u16* __restrict__ WvT,
    u16* __restrict__ WoT)
{
    int id = blockIdx.x * 256 + threadIdx.x;       // 524288 total
    if (id < 393216) {
        int w = id / 131072;
        int r = id % 131072;
        int c = r >> 8;       // 0..511
        int d = r & 255;      // 0..255
        const float* W = (w == 0) ? Wq : (w == 1 ? Wk : Wv);
        u16* WT = (w == 0) ? WqT : (w == 1 ? WkT : WvT);
        WT[c * 256 + d] = f2bf(W[(c >> 6) * (256 * 64) + d * 64 + (c & 63)]);
    } else {
        int r = id - 393216;  // 0..131071
        int o = r >> 9;       // 0..255
        int k = r & 511;      // 0..511
        WoT[o * 512 + k] = f2bf(Wo[k * 256 + o]);
    }
}

// ---------------- kernel 1: QKV projection GEMM ----------------
// X[4096][256] (fp32) @ WT^T -> per-head outputs, bf16.
// grid (64 mtiles, 8 ntiles, 3 which), 256 threads.
// which 0: Q (scaled 0.125) -> Qb[bh][n][e]
// which 1: K -> Kb[bh][n][e]
// which 2: V -> Vt[bh][e][n]   (transposed!)
__global__ __launch_bounds__(256) void proj_kernel(
    const float* __restrict__ feat, const float* __restrict__ query,
    const u16* __restrict__ WqT, const u16* __restrict__ WkT, const u16* __restrict__ WvT,
    const float* __restrict__ bq, const float* __restrict__ bk, const float* __restrict__ bv,
    u16* __restrict__ Qb, u16* __restrict__ Kb, u16* __restrict__ Vt)
{
    int which = blockIdx.z;
    const float* X = (which == 0) ? query : feat;
    const u16* WT = (which == 0) ? WqT : (which == 1 ? WkT : WvT);
    const float* bias = (which == 0) ? bq : (which == 1 ? bk : bv);
    int m0 = blockIdx.x * 64;
    int n0 = blockIdx.y * 64;
    int t = threadIdx.x;
    int lane = t & 63, w = t >> 6;
    int l15 = lane & 15, kof = (lane >> 4) * 8;

    __shared__ __align__(16) u16 lA[64][72];
    __shared__ __align__(16) u16 lB[64][72];

    f32x4 acc[4] = {};
    for (int kt = 0; kt < 256; kt += 64) {
        // stage A: 64x64 fp32 -> bf16
        #pragma unroll
        for (int i = 0; i < 4; i++) {
            int lin = t + i * 256;            // 1024 lins x 4 floats
            int row = lin >> 4, c4 = (lin & 15) * 4;
            float4 v = *reinterpret_cast<const float4*>(&X[(m0 + row) * 256 + kt + c4]);
            lA[row][c4 + 0] = f2bf(v.x);
            lA[row][c4 + 1] = f2bf(v.y);
            lA[row][c4 + 2] = f2bf(v.z);
            lA[row][c4 + 3] = f2bf(v.w);
        }
        // stage B: 64x64 bf16
        #pragma unroll
        for (int i = 0; i < 2; i++) {
            int lin = t + i * 256;            // 512 lins x 8 bf16
            int row = lin >> 3, c8 = (lin & 7) * 8;
            *reinterpret_cast<uint4*>(&lB[row][c8]) =
                *reinterpret_cast<const uint4*>(&WT[(n0 + row) * 256 + kt + c8]);
        }
        __syncthreads();
        #pragma unroll
        for (int ks = 0; ks < 2; ks++) {
            short8 a = *reinterpret_cast<const short8*>(&lA[w * 16 + l15][ks * 32 + kof]);
            #pragma unroll
            for (int nt = 0; nt < 4; nt++) {
                short8 b = *reinterpret_cast<const short8*>(&lB[nt * 16 + l15][ks * 32 + kof]);
                acc[nt] = __builtin_amdgcn_mfma_f32_16x16x32_bf16(a, b, acc[nt], 0, 0, 0);
            }
        }
        __syncthreads();
    }
    // epilogue
    #pragma unroll
    for (int nt = 0; nt < 4; nt++) {
        #pragma unroll
        for (int i = 0; i < 4; i++) {
            int mrow = m0 + w * 16 + (lane >> 4) * 4 + i;
            int col = n0 + nt * 16 + l15;
            float val = acc[nt][i] + bias[col];
            int b_ = mrow >> 11, nq = mrow & 2047;
            int h = col >> 6, e = col & 63;
            int bh = b_ * 8 + h;
            if (which == 0) {
                Qb[(bh * 2048 + nq) * 64 + e] = f2bf(val * 0.125f);
            } else if (which == 1) {
                Kb[(bh * 2048 + nq) * 64 + e] = f2bf(val);
            } else {
                Vt[(bh * 64 + e) * 2048 + nq] = f2bf(val);
            }
        }
    }
}

// ---------------- kernel 2: flash attention ----------------
// grid (32 qtiles, 16 bh), 256 threads (4 waves x 16 q-rows).
__global__ __launch_bounds__(256) void attn_kernel(
    const u16* __restrict__ Qb, const u16* __restrict__ Kb,
    const u16* __restrict__ Vt, u16* __restrict__ cat)
{
    int qt = blockIdx.x;
    int bh = blockIdx.y;
    int b_ = bh >> 3, h = bh & 7;
    int t = threadIdx.x, lane = t & 63, w = t >> 6;
    int l15 = lane & 15, kof = (lane >> 4) * 8;

    __shared__ __align__(16) u16 lK[64][72];
    __shared__ __align__(16) u16 lV[64][72];        // lV[hid][kv]
    __shared__ __align__(16) u16 lP[4][16][72];

    const u16* Qrow = Qb + (bh * 2048 + qt * 64) * 64;
    const u16* Krow = Kb + bh * 2048 * 64;
    const u16* Vrow = Vt + bh * 64 * 2048;

    short8 aq[2];
    {
        int qr = w * 16 + l15;
        aq[0] = *reinterpret_cast<const short8*>(&Qrow[qr * 64 + 0 + kof]);
        aq[1] = *reinterpret_cast<const short8*>(&Qrow[qr * 64 + 32 + kof]);
    }

    f32x4 o[4] = {};
    float mrun[4] = {-INFINITY, -INFINITY, -INFINITY, -INFINITY};
    float lrun[4] = {0.f, 0.f, 0.f, 0.f};

    for (int kv0 = 0; kv0 < 2048; kv0 += 64) {
        #pragma unroll
        for (int i = 0; i < 2; i++) {
            int lin = t + i * 256;
            int row = lin >> 3, c8 = (lin & 7) * 8;
            *reinterpret_cast<uint4*>(&lK[row][c8]) =
                *reinterpret_cast<const uint4*>(&Krow[(kv0 + row) * 64 + c8]);
            *reinterpret_cast<uint4*>(&lV[row][c8]) =
                *reinterpret_cast<const uint4*>(&Vrow[row * 2048 + kv0 + c8]);
        }
        __syncthreads();

        // QK^T: S = 16x64 per wave
        f32x4 s[4] = {};
        #pragma unroll
        for (int ks = 0; ks < 2; ks++) {
            #pragma unroll
            for (int nt = 0; nt < 4; nt++) {
                short8 bk_ = *reinterpret_cast<const short8*>(&lK[nt * 16 + l15][ks * 32 + kof]);
                s[nt] = __builtin_amdgcn_mfma_f32_16x16x32_bf16(aq[ks], bk_, s[nt], 0, 0, 0);
            }
        }

        // online softmax (row = (lane>>4)*4 + i, 64 cols spread over 16 lanes x 4 nt)
        #pragma unroll
        for (int i = 0; i < 4; i++) {
            float mx = fmaxf(fmaxf(s[0][i], s[1][i]), fmaxf(s[2][i], s[3][i]));
            mx = fmaxf(mx, __shfl_xor(mx, 1));
            mx = fmaxf(mx, __shfl_xor(mx, 2));
            mx = fmaxf(mx, __shfl_xor(mx, 4));
            mx = fmaxf(mx, __shfl_xor(mx, 8));
            float mn = fmaxf(mrun[i], mx);
            float corr = __expf(mrun[i] - mn);
            mrun[i] = mn;
            float sum = 0.f;
            #pragma unroll
            for (int nt = 0; nt < 4; nt++) {
                float p = __expf(s[nt][i] - mn);
                s[nt][i] = p;
                sum += p;
            }
            sum += __shfl_xor(sum, 1);
            sum += __shfl_xor(sum, 2);
            sum += __shfl_xor(sum, 4);
            sum += __shfl_xor(sum, 8);
            lrun[i] = lrun[i] * corr + sum;
            #pragma unroll
            for (int nt = 0; nt < 4; nt++) o[nt][i] *= corr;
        }

        // P -> LDS (C layout -> A layout round trip), per-wave private region
        #pragma unroll
        for (int i = 0; i < 4; i++) {
            int pr = (lane >> 4) * 4 + i;
            #pragma unroll
            for (int nt = 0; nt < 4; nt++)
                lP[w][pr][nt * 16 + l15] = f2bf(s[nt][i]);
        }

        // PV: o += P @ V
        #pragma unroll
        for (int ks = 0; ks < 2; ks++) {
            short8 ap = *reinterpret_cast<const short8*>(&lP[w][l15][ks * 32 + kof]);
            #pragma unroll
            for (int nt = 0; nt < 4; nt++) {
                short8 bv_ = *reinterpret_cast<const short8*>(&lV[nt * 16 + l15][ks * 32 + kof]);
                o[nt] = __builtin_amdgcn_mfma_f32_16x16x32_bf16(ap, bv_, o[nt], 0, 0, 0);
            }
        }
        __syncthreads();
    }

    // epilogue: normalize and write cat[b*2048+q][h*64+hid] (bf16)
    int qbase = qt * 64 + w * 16;
    #pragma unroll
    for (int i = 0; i < 4; i++) {
        int qr = qbase + (lane >> 4) * 4 + i;
        float inv = 1.0f / lrun[i];
        #pragma unroll
        for (int nt = 0; nt < 4; nt++) {
            cat[(b_ * 2048 + qr) * 512 + h * 64 + nt * 16 + l15] = f2bf(o[nt][i] * inv);
        }
    }
}

// ---------------- kernel 3: output projection ----------------
// cat[4096][512] (bf16) @ Wo[512][256] + bo -> out fp32 [4096][256]
// grid (64 mtiles, 4 ntiles), 256 threads.
__global__ __launch_bounds__(256) void outproj_kernel(
    const u16* __restrict__ cat, const u16* __restrict__ WoT,
    const float* __restrict__ bo, float* __restrict__ out)
{
    int m0 = blockIdx.x * 64, n0 = blockIdx.y * 64;
    int t = threadIdx.x, lane = t & 63, w = t >> 6;
    int l15 = lane & 15, kof = (lane >> 4) * 8;

    __shared__ __align__(16) u16 lA[64][72];
    __shared__ __align__(16) u16 lB[64][72];

    f32x4 acc[4] = {};
    for (int kt = 0; kt < 512; kt += 64) {
        #pragma unroll
        for (int i = 0; i < 2; i++) {
            int lin = t + i * 256;
            int row = lin >> 3, c8 = (lin & 7) * 8;
            *reinterpret_cast<uint4*>(&lA[row][c8]) =
                *reinterpret_cast<const uint4*>(&cat[(m0 + row) * 512 + kt + c8]);
            *reinterpret_cast<uint4*>(&lB[row][c8]) =
                *reinterpret_cast<const uint4*>(&WoT[(n0 + row) * 512 + kt + c8]);
        }
        __syncthreads();
        #pragma unroll
        for (int ks = 0; ks < 2; ks++) {
            short8 a = *reinterpret_cast<const short8*>(&lA[w * 16 + l15][ks * 32 + kof]);
            #pragma unroll
            for (int nt = 0; nt < 4; nt++) {
                short8 b = *reinterpret_cast<const short8*>(&lB[nt * 16 + l15][ks * 32 + kof]);
                acc[nt] = __builtin_amdgcn_mfma_f32_16x16x32_bf16(a, b, acc[nt], 0, 0, 0);
            }
        }
        __syncthreads();
    }
    #pragma unroll
    for (int i = 0; i < 4; i++) {
        int mrow = m0 + w * 16 + (lane >> 4) * 4 + i;
        #pragma unroll
        for (int nt = 0; nt < 4; nt++) {
            int col = n0 + nt * 16 + l15;
            out[mrow * 256 + col] = acc[nt][i] + bo[col];
        }
    }
}

extern "C" void kernel_launch(void* const* d_in, const int* in_sizes, int n_in,
                              void* d_out, int out_size, void* d_ws, size_t ws_size,
                              hipStream_t stream) {
    const float* feat  = (const float*)d_in[0];
    const float* query = (const float*)d_in[1];
    const float* Wq = (const float*)d_in[2];
    const float* bq = (const float*)d_in[3];
    const float* Wk = (const float*)d_in[4];
    const float* bk = (const float*)d_in[5];
    const float* Wv = (const float*)d_in[6];
    const float* bv = (const float*)d_in[7];
    const float* Wo = (const float*)d_in[8];
    const float* bo = (const float*)d_in[9];
    float* out = (float*)d_out;

    char* ws = (char*)d_ws;
    u16* WqT = (u16*)(ws + 0);
    u16* WkT = (u16*)(ws + 262144);
    u16* WvT = (u16*)(ws + 524288);
    u16* WoT = (u16*)(ws + 786432);
    u16* Qb  = (u16*)(ws + 1048576);
    u16* Kb  = (u16*)(ws + 1048576 + 4194304);
    u16* Vt  = (u16*)(ws + 1048576 + 8388608);
    u16* cat = (u16*)(ws + 1048576 + 12582912);

    hipLaunchKernelGGL(prep_weights, dim3(2048), dim3(256), 0, stream,
                       Wq, Wk, Wv, Wo, WqT, WkT, WvT, WoT);
    hipLaunchKernelGGL(proj_kernel, dim3(64, 8, 3), dim3(256), 0, stream,
                       feat, query, WqT, WkT, WvT, bq, bk, bv, Qb, Kb, Vt);
    hipLaunchKernelGGL(attn_kernel, dim3(32, 16), dim3(256), 0, stream,
                       Qb, Kb, Vt, cat);
    hipLaunchKernelGGL(outproj_kernel, dim3(64, 4), dim3(256), 0, stream,
                       cat, WoT, bo, out);
}

// Round 3
// 93.844 us; speedup vs baseline: 1.0901x; 1.0901x over previous
//
#include <hip/hip_runtime.h>
#include <hip/hip_bf16.h>

typedef unsigned short u16;
typedef __attribute__((ext_vector_type(8))) short short8;
typedef __attribute__((ext_vector_type(4))) float f32x4;
typedef __attribute__((ext_vector_type(16))) float f32x16;
typedef __attribute__((ext_vector_type(2))) int v2i;

#define HEADS 8
#define HID 64
// 0.125 * log2(e): scores computed in log2 domain so softmax uses raw v_exp_f32
#define QSCALE 0.18033688011112042f

__device__ inline u16 f2bf(float f){
    unsigned u = __float_as_uint(f);
    unsigned r = (u + 0x7fffu + ((u >> 16) & 1u)) >> 16;
    return (u16)r;
}

__device__ inline int cvtpk(float lo, float hi){
    int r;
    asm("v_cvt_pk_bf16_f32 %0, %1, %2" : "=v"(r) : "v"(lo), "v"(hi));
    return r;
}

// 2^x via the HW transcendental (scores are in log2 domain)
__device__ inline float exp2fast(float x){
    float r;
    asm("v_exp_f32 %0, %1" : "=v"(r) : "v"(x));
    return r;
}

// ---------------- kernel 0: weight prep (transpose -> bf16) ----------------
__global__ __launch_bounds__(256) void prep_weights(
    const float* __restrict__ Wq, const float* __restrict__ Wk,
    const float* __restrict__ Wv, const float* __restrict__ Wo,
    u16* __restrict__ WqT, u16* __restrict__ WkT, u16* __restrict__ WvT,
    u16* __restrict__ WoT)
{
    int id = blockIdx.x * 256 + threadIdx.x;       // 524288 total
    if (id < 393216) {
        int w = id / 131072;
        int r = id % 131072;
        int c = r >> 8;       // 0..511
        int d = r & 255;      // 0..255
        const float* W = (w == 0) ? Wq : (w == 1 ? Wk : Wv);
        u16* WT = (w == 0) ? WqT : (w == 1 ? WkT : WvT);
        WT[c * 256 + d] = f2bf(W[(c >> 6) * (256 * 64) + d * 64 + (c & 63)]);
    } else {
        int r = id - 393216;
        int o = r >> 9;
        int k = r & 511;
        WoT[o * 512 + k] = f2bf(Wo[k * 256 + o]);
    }
}

// ---------------- kernel 1: QKV projection GEMM ----------------
__global__ __launch_bounds__(256) void proj_kernel(
    const float* __restrict__ feat, const float* __restrict__ query,
    const u16* __restrict__ WqT, const u16* __restrict__ WkT, const u16* __restrict__ WvT,
    const float* __restrict__ bq, const float* __restrict__ bk, const float* __restrict__ bv,
    u16* __restrict__ Qb, u16* __restrict__ Kb, u16* __restrict__ Vt)
{
    int which = blockIdx.z;
    const float* X = (which == 0) ? query : feat;
    const u16* WT = (which == 0) ? WqT : (which == 1 ? WkT : WvT);
    const float* bias = (which == 0) ? bq : (which == 1 ? bk : bv);
    int m0 = blockIdx.x * 64;
    int n0 = blockIdx.y * 64;
    int t = threadIdx.x;
    int lane = t & 63, w = t >> 6;
    int l15 = lane & 15, kof = (lane >> 4) * 8;

    __shared__ __align__(16) u16 lA[64][72];
    __shared__ __align__(16) u16 lB[64][72];

    f32x4 acc[4] = {};
    for (int kt = 0; kt < 256; kt += 64) {
        #pragma unroll
        for (int i = 0; i < 4; i++) {
            int lin = t + i * 256;
            int row = lin >> 4, c4 = (lin & 15) * 4;
            float4 v = *reinterpret_cast<const float4*>(&X[(m0 + row) * 256 + kt + c4]);
            lA[row][c4 + 0] = f2bf(v.x);
            lA[row][c4 + 1] = f2bf(v.y);
            lA[row][c4 + 2] = f2bf(v.z);
            lA[row][c4 + 3] = f2bf(v.w);
        }
        #pragma unroll
        for (int i = 0; i < 2; i++) {
            int lin = t + i * 256;
            int row = lin >> 3, c8 = (lin & 7) * 8;
            *reinterpret_cast<uint4*>(&lB[row][c8]) =
                *reinterpret_cast<const uint4*>(&WT[(n0 + row) * 256 + kt + c8]);
        }
        __syncthreads();
        #pragma unroll
        for (int ks = 0; ks < 2; ks++) {
            short8 a = *reinterpret_cast<const short8*>(&lA[w * 16 + l15][ks * 32 + kof]);
            #pragma unroll
            for (int nt = 0; nt < 4; nt++) {
                short8 b = *reinterpret_cast<const short8*>(&lB[nt * 16 + l15][ks * 32 + kof]);
                acc[nt] = __builtin_amdgcn_mfma_f32_16x16x32_bf16(a, b, acc[nt], 0, 0, 0);
            }
        }
        __syncthreads();
    }
    #pragma unroll
    for (int nt = 0; nt < 4; nt++) {
        #pragma unroll
        for (int i = 0; i < 4; i++) {
            int mrow = m0 + w * 16 + (lane >> 4) * 4 + i;
            int col = n0 + nt * 16 + l15;
            float val = acc[nt][i] + bias[col];
            int b_ = mrow >> 11, nq = mrow & 2047;
            int h = col >> 6, e = col & 63;
            int bh = b_ * 8 + h;
            if (which == 0) {
                Qb[(bh * 2048 + nq) * 64 + e] = f2bf(val * QSCALE);
            } else if (which == 1) {
                Kb[(bh * 2048 + nq) * 64 + e] = f2bf(val);
            } else {
                Vt[(bh * 64 + e) * 2048 + nq] = f2bf(val);
            }
        }
    }
}

// ---------------- kernel 2: flash attention, swapped-operand 32x32, no LDS --------
// grid: 256 blocks x 256 threads. 4 waves/block, each wave owns 32 q-rows.
// Per wave: S^T = mfma32x32x16(K, Q); in-register softmax (lane = one q column);
// P->bf16 B-frags via cvt_pk + permlane32_swap; O^T += mfma(V^T, P^T).
__global__ __launch_bounds__(256, 1) void attn_kernel(
    const u16* __restrict__ Qb, const u16* __restrict__ Kb,
    const u16* __restrict__ Vt, u16* __restrict__ cat)
{
    int lb = blockIdx.x;
    // XCD-aware mapping: XCD = lb%8 gets bh in {2*(lb%8), 2*(lb%8)+1} -> K/V L2-resident
    int qt = lb >> 4;
    int bh = ((lb & 7) << 1) | ((lb >> 3) & 1);
    int b_ = bh >> 3, head = bh & 7;
    int t = threadIdx.x, lane = t & 63, w = t >> 6;
    int l31 = lane & 31, hh = lane >> 5;
    int q0 = qt * 128 + w * 32;

    const u16* Kl = Kb + bh * 131072 + l31 * 64 + hh * 8;     // + kv*64 (+c2*2048) + kc*16
    const u16* Vl = Vt + bh * 131072 + l31 * 2048 + hh * 8;   // + eb*65536 + kv0 + c*16

    // Q B-fragments (col = q = l31, k = d), held in regs for the whole loop
    short8 qf[4];
    {
        const u16* qp = Qb + (bh * 2048 + q0 + l31) * 64 + hh * 8;
        #pragma unroll
        for (int kc = 0; kc < 4; kc++)
            qf[kc] = *reinterpret_cast<const short8*>(qp + kc * 16);
    }

    f32x16 o0 = {}, o1 = {};
    float mrun = -1e30f, lrun = 0.0f;

#define PACKP(sb, base, out) {                                              \
        int A0 = cvtpk(sb[base+0], sb[base+1]);                             \
        int B0 = cvtpk(sb[base+4], sb[base+5]);                             \
        v2i r0 = __builtin_amdgcn_permlane32_swap(A0, B0, false, false);    \
        int A1 = cvtpk(sb[base+2], sb[base+3]);                             \
        int B1 = cvtpk(sb[base+6], sb[base+7]);                             \
        v2i r1 = __builtin_amdgcn_permlane32_swap(A1, B1, false, false);    \
        union { int i[4]; short8 s; } uu;                                   \
        uu.i[0] = r0.x; uu.i[1] = r1.x; uu.i[2] = r0.y; uu.i[3] = r1.y;     \
        out = uu.s; }

    auto loadK = [&](short8 (&kf)[8], int tt) {
        const u16* p = Kl + (tt & 31) * 4096;
        #pragma unroll
        for (int c2 = 0; c2 < 2; c2++)
            #pragma unroll
            for (int kc = 0; kc < 4; kc++)
                kf[c2 * 4 + kc] = *reinterpret_cast<const short8*>(p + c2 * 2048 + kc * 16);
    };

    auto compute = [&](short8 (&kf)[8], int tt) {
        const u16* vp = Vl + tt * 64;
        short8 vf[8];
        #pragma unroll
        for (int eb = 0; eb < 2; eb++)
            #pragma unroll
            for (int c = 0; c < 4; c++)
                vf[eb * 4 + c] = *reinterpret_cast<const short8*>(vp + eb * 65536 + c * 16);

        f32x16 s0 = {}, s1 = {};
        #pragma unroll
        for (int kc = 0; kc < 4; kc++)
            s0 = __builtin_amdgcn_mfma_f32_32x32x16_bf16(kf[kc], qf[kc], s0, 0, 0, 0);
        #pragma unroll
        for (int kc = 0; kc < 4; kc++)
            s1 = __builtin_amdgcn_mfma_f32_32x32x16_bf16(kf[4 + kc], qf[kc], s1, 0, 0, 0);

        // ---- in-register online softmax (log2 domain), lane holds one q column ----
        float pmax = -1e30f;
        #pragma unroll
        for (int r = 0; r < 16; r++) pmax = fmaxf(pmax, fmaxf(s0[r], s1[r]));
        pmax = fmaxf(pmax, __shfl_xor(pmax, 32));
        if (__any(pmax > mrun + 6.0f)) {        // defer-max (T13), log2 units
            float mnew = fmaxf(mrun, pmax);
            float corr = exp2fast(mrun - mnew);
            mrun = mnew;
            lrun *= corr;
            #pragma unroll
            for (int r = 0; r < 16; r++) { o0[r] *= corr; o1[r] *= corr; }
        }
        float lsum = 0.0f;
        #pragma unroll
        for (int r = 0; r < 16; r++) {
            float p0 = exp2fast(s0[r] - mrun);
            float p1 = exp2fast(s1[r] - mrun);
            s0[r] = p0; s1[r] = p1;
            lsum += p0 + p1;
        }
        lsum += __shfl_xor(lsum, 32);
        lrun += lsum;

        // ---- pack P^T into B-fragments (T12) ----
        short8 pf[4];
        PACKP(s0, 0, pf[0]); PACKP(s0, 8, pf[1]);
        PACKP(s1, 0, pf[2]); PACKP(s1, 8, pf[3]);

        // ---- PV: O^T += V^T @ P^T ----
        #pragma unroll
        for (int c = 0; c < 4; c++) {
            o0 = __builtin_amdgcn_mfma_f32_32x32x16_bf16(vf[c],     pf[c], o0, 0, 0, 0);
            o1 = __builtin_amdgcn_mfma_f32_32x32x16_bf16(vf[4 + c], pf[c], o1, 0, 0, 0);
        }
    };

    short8 ka[8], kb2[8];
    loadK(ka, 0);
    for (int tt = 0; tt < 32; tt += 2) {
        loadK(kb2, tt + 1);     // prefetch next K tile while computing current
        compute(ka, tt);
        loadK(ka, tt + 2);
        compute(kb2, tt + 1);
    }

    // ---- epilogue: normalize, write cat[b][q][head*64+e] ----
    float inv = 1.0f / lrun;
    u16* crow = cat + (b_ * 2048 + q0 + l31) * 512 + head * 64;
    #pragma unroll
    for (int eb = 0; eb < 2; eb++) {
        #pragma unroll
        for (int rg = 0; rg < 4; rg++) {
            int ebase = 32 * eb + 8 * rg + 4 * hh;
            float a0 = (eb ? o1[rg*4+0] : o0[rg*4+0]) * inv;
            float a1 = (eb ? o1[rg*4+1] : o0[rg*4+1]) * inv;
            float a2 = (eb ? o1[rg*4+2] : o0[rg*4+2]) * inv;
            float a3 = (eb ? o1[rg*4+3] : o0[rg*4+3]) * inv;
            v2i st;
            st.x = cvtpk(a0, a1);
            st.y = cvtpk(a2, a3);
            *reinterpret_cast<v2i*>(crow + ebase) = st;
        }
    }
#undef PACKP
}

// ---------------- kernel 3: output projection ----------------
__global__ __launch_bounds__(256) void outproj_kernel(
    const u16* __restrict__ cat, const u16* __restrict__ WoT,
    const float* __restrict__ bo, float* __restrict__ out)
{
    int m0 = blockIdx.x * 64, n0 = blockIdx.y * 64;
    int t = threadIdx.x, lane = t & 63, w = t >> 6;
    int l15 = lane & 15, kof = (lane >> 4) * 8;

    __shared__ __align__(16) u16 lA[64][72];
    __shared__ __align__(16) u16 lB[64][72];

    f32x4 acc[4] = {};
    for (int kt = 0; kt < 512; kt += 64) {
        #pragma unroll
        for (int i = 0; i < 2; i++) {
            int lin = t + i * 256;
            int row = lin >> 3, c8 = (lin & 7) * 8;
            *reinterpret_cast<uint4*>(&lA[row][c8]) =
                *reinterpret_cast<const uint4*>(&cat[(m0 + row) * 512 + kt + c8]);
            *reinterpret_cast<uint4*>(&lB[row][c8]) =
                *reinterpret_cast<const uint4*>(&WoT[(n0 + row) * 512 + kt + c8]);
        }
        __syncthreads();
        #pragma unroll
        for (int ks = 0; ks < 2; ks++) {
            short8 a = *reinterpret_cast<const short8*>(&lA[w * 16 + l15][ks * 32 + kof]);
            #pragma unroll
            for (int nt = 0; nt < 4; nt++) {
                short8 b = *reinterpret_cast<const short8*>(&lB[nt * 16 + l15][ks * 32 + kof]);
                acc[nt] = __builtin_amdgcn_mfma_f32_16x16x32_bf16(a, b, acc[nt], 0, 0, 0);
            }
        }
        __syncthreads();
    }
    #pragma unroll
    for (int i = 0; i < 4; i++) {
        int mrow = m0 + w * 16 + (lane >> 4) * 4 + i;
        #pragma unroll
        for (int nt = 0; nt < 4; nt++) {
            int col = n0 + nt * 16 + l15;
            out[mrow * 256 + col] = acc[nt][i] + bo[col];
        }
    }
}

extern "C" void kernel_launch(void* const* d_in, const int* in_sizes, int n_in,
                              void* d_out, int out_size, void* d_ws, size_t ws_size,
                              hipStream_t stream) {
    const float* feat  = (const float*)d_in[0];
    const float* query = (const float*)d_in[1];
    const float* Wq = (const float*)d_in[2];
    const float* bq = (const float*)d_in[3];
    const float* Wk = (const float*)d_in[4];
    const float* bk = (const float*)d_in[5];
    const float* Wv = (const float*)d_in[6];
    const float* bv = (const float*)d_in[7];
    const float* Wo = (const float*)d_in[8];
    const float* bo = (const float*)d_in[9];
    float* out = (float*)d_out;

    char* ws = (char*)d_ws;
    u16* WqT = (u16*)(ws + 0);
    u16* WkT = (u16*)(ws + 262144);
    u16* WvT = (u16*)(ws + 524288);
    u16* WoT = (u16*)(ws + 786432);
    u16* Qb  = (u16*)(ws + 1048576);
    u16* Kb  = (u16*)(ws + 1048576 + 4194304);
    u16* Vt  = (u16*)(ws + 1048576 + 8388608);
    u16* cat = (u16*)(ws + 1048576 + 12582912);

    hipLaunchKernelGGL(prep_weights, dim3(2048), dim3(256), 0, stream,
                       Wq, Wk, Wv, Wo, WqT, WkT, WvT, WoT);
    hipLaunchKernelGGL(proj_kernel, dim3(64, 8, 3), dim3(256), 0, stream,
                       feat, query, WqT, WkT, WvT, bq, bk, bv, Qb, Kb, Vt);
    hipLaunchKernelGGL(attn_kernel, dim3(256), dim3(256), 0, stream,
                       Qb, Kb, Vt, cat);
    hipLaunchKernelGGL(outproj_kernel, dim3(64, 4), dim3(256), 0, stream,
                       cat, WoT, bo, out);
}